// Round 3
// baseline (27160.870 us; speedup 1.0000x reference)
//
#include <hip/hip_runtime.h>

typedef unsigned long long u64;
typedef unsigned int u32;

// ---------------- problem constants ----------------
#define Bz 32
#define Sz 128
#define Ez 256
#define Hz 256
#define Vz 16000
#define Tz 128

// ---------------- workspace layout (bytes), total 1.28MB ----------------
#define OFF_PART 8192u       // u64[32*1024] = 256KB
#define OFF_HS   524288u     // float[196608] = 768KB
// scratch in OUT buffer (f32 out = 262MB; region overwritten later by k_dec):
#define OUT_XS   0u          // float[128*32*256] = 4MB
#define OUT_XS1  (4u<<20)    // float[128*32*512] = 8MB

// HS float-index offsets
// encoder chains: base = layer*49152 + chain*24576 ; hbuf0=+0, hbuf1=+8192, c=+16384
#define HS_H0A 98304
#define HS_H0B 114688
#define HS_C0  131072
#define HS_H1A 147456
#define HS_H1B 163840
#define HS_C1  180224
#define HS_N   196608

__device__ inline float sigf(float x){ return 1.0f/(1.0f+expf(-x)); }
__device__ inline u32 f2ord(float f){ u32 u=__float_as_uint(f); return (u & 0x80000000u) ? ~u : (u | 0x80000000u); }

#define ACC4(w, xp) { acc=fmaf((w).x,(xp)[0],acc); acc=fmaf((w).y,(xp)[1],acc); \
                      acc=fmaf((w).z,(xp)[2],acc); acc=fmaf((w).w,(xp)[3],acc); }

struct BarSlot { u32 cnt; u32 gen; };

// Generation barrier. Leader resets cnt before release-incrementing gen;
// waiters acquire on gen (publishes all participants' prior writes, agent scope).
__device__ inline void block_bar(BarSlot* s, u32 nblk, u32 target){
  __syncthreads();
  if (threadIdx.x == 0){
    u32 old = __hip_atomic_fetch_add(&s->cnt, 1u, __ATOMIC_ACQ_REL, __HIP_MEMORY_SCOPE_AGENT);
    if (old == nblk-1u){
      __hip_atomic_store(&s->cnt, 0u, __ATOMIC_RELAXED, __HIP_MEMORY_SCOPE_AGENT);
      __hip_atomic_fetch_add(&s->gen, 1u, __ATOMIC_RELEASE, __HIP_MEMORY_SCOPE_AGENT);
    } else {
      while (__hip_atomic_load(&s->gen, __ATOMIC_ACQUIRE, __HIP_MEMORY_SCOPE_AGENT) < target){
        __builtin_amdgcn_s_sleep(2);
      }
    }
  }
  __syncthreads();
}

__device__ inline u64 shfl_down_u64(u64 x, int d){
  int lo = __shfl_down((int)(u32)(x & 0xFFFFFFFFull), d, 64);
  int hi = __shfl_down((int)(u32)(x >> 32), d, 64);
  return (((u64)(u32)hi)<<32) | (u64)(u32)lo;
}

// ================= init: embed (f32) into out-scratch, zero states/partials =================
__global__ __launch_bounds__(256) void k_init(const int* __restrict__ inp,
    const float* __restrict__ iemb, char* __restrict__ outc, char* __restrict__ ws)
{
  float4* XS4 = (float4*)(outc + OUT_XS);
  const float4* IE4 = (const float4*)iemb;
  float4* HS4 = (float4*)(ws + OFF_HS);
  u64* PART = (u64*)(ws + OFF_PART);
  const int N1 = 262144;          // XS float4: [128][32][64]
  const int N2 = HS_N/4;          // 49152
  const int N3 = 32768;           // PART u64
  const int TOT = N1+N2+N3;
  for (int i = blockIdx.x*256 + threadIdx.x; i < TOT; i += gridDim.x*256){
    int r = i;
    if (r < N1){
      int e4 = r & 63, sb = r >> 6;
      int b2 = sb & 31, s2 = sb >> 5;
      XS4[r] = IE4[(size_t)inp[b2*Sz + s2]*64 + e4];
    } else if ((r -= N1) < N2){
      HS4[r] = make_float4(0.f,0.f,0.f,0.f);
    } else {
      PART[r - N2] = 0ull;
    }
  }
}

// ================= encoder layer scan (both directions concurrently) =================
// grid 256: blocks [0,128) fwd chain, [128,256) bwd.  c=blk&127: b=c&31, q=c>>5.
// thread=(g,jj): one gate-row dot. Cell by tid<64. One 4-block barrier/step; h ping-pong.
__global__ __launch_bounds__(256) void k_enc(
    const float* __restrict__ Wfi, const float* __restrict__ Wfh, const float* __restrict__ bfv,
    const float* __restrict__ Wbi, const float* __restrict__ Wbh, const float* __restrict__ bbv,
    char* __restrict__ outc, char* __restrict__ ws, int layer)
{
  __shared__ __align__(16) float xh[1024];   // x (<=512) + h (256); glds at +768
  float* glds = xh + 768;
  int tid = threadIdx.x;
  int chain = blockIdx.x >> 7, c = blockIdx.x & 127;
  int b = c & 31, q = c >> 5, j0 = q*64;
  int g = tid >> 6, jj = tid & 63;
  int xK = layer ? 512 : 256;
  const float* X    = (const float*)(outc + (layer ? OUT_XS1 : OUT_XS));
  float*       XS1w = (float*)(outc + OUT_XS1);
  float* HSf = (float*)(ws + OFF_HS);
  float* chbase = HSf + layer*49152 + chain*24576;
  float* cst = chbase + 16384;
  const float* Wih  = chain ? Wbi : Wfi;
  const float* Whh  = chain ? Wbh : Wfh;
  const float* bias = chain ? bbv : bfv;
  int row = g*256 + j0 + jj;
  float bv = bias[row];
  BarSlot* bar = (BarSlot*)ws + (layer ? 64 : 0) + chain*32 + b;
  int dh_off = layer ? HS_H1A : HS_H0A;
  int dc_off = layer ? HS_C1  : HS_C0;
  const float4* wa  = (const float4*)(Wih + (size_t)row*xK);
  const float4* wb2 = (const float4*)(Whh + (size_t)row*256);

  for (int s = 0; s < 128; ++s){
    int xi = chain ? (127 - s) : s;
    const float* hbuf = chbase + (s&1)*8192;
    const float* xrow = X + ((size_t)xi*32 + b)*xK;
    xh[tid] = xrow[tid];
    if (layer) xh[256 + tid] = xrow[256 + tid];
    xh[xK + tid] = hbuf[b*256 + tid];
    __syncthreads();
    float acc = bv;
    int nA4 = xK >> 2;
    #pragma unroll 16
    for (int k4 = 0; k4 < nA4; ++k4){ float4 w = wa[k4]; ACC4(w, xh + (k4<<2)); }
    #pragma unroll 16
    for (int k4 = 0; k4 < 64; ++k4){ float4 w = wb2[k4]; ACC4(w, xh + xK + (k4<<2)); }
    glds[tid] = acc;
    __syncthreads();
    if (tid < 64){
      int j = j0 + tid;
      float iv = sigf(glds[tid]), fv = sigf(glds[64+tid]);
      float gv = tanhf(glds[128+tid]), ov = sigf(glds[192+tid]);
      float cold = cst[b*256 + j];
      float cnew = fv*cold + iv*gv;
      cst[b*256 + j] = cnew;
      float hnew = ov*tanhf(cnew);
      (chbase + ((s+1)&1)*8192)[b*256 + j] = hnew;
      if (layer == 0) XS1w[((size_t)xi*32 + b)*512 + chain*256 + j] = hnew;
      if (s == 127){
        HSf[dh_off + b*512 + chain*256 + j] = hnew;
        HSf[dc_off + b*512 + chain*256 + j] = cnew;
      }
    }
    if (s < 127) block_bar(bar, 4, (u32)(s+1));
  }
}

// ================= decoder: 127 greedy steps =================
// grid 256. b=(blk&7)|((blk>>6)<<3), jgrp=(blk>>3)&7 (8 blocks of b share blk%8 -> same XCD).
// Linear: blocks 0..249 cover 64 v; thread=(vl 0..7 -> 8 v, bb 0..31 -> batch).
__global__ __launch_bounds__(256) void k_dec(const float* __restrict__ oemb,
    const float* __restrict__ W0i, const float* __restrict__ W0h, const float* __restrict__ b0v,
    const float* __restrict__ W1i, const float* __restrict__ W1h, const float* __restrict__ b1v,
    const float* __restrict__ linW, const float* __restrict__ linbv, const int* __restrict__ clsp,
    float* __restrict__ out, char* __restrict__ ws)
{
  __shared__ __align__(16) float smem[16384];  // 64KB: A/B: xh[1024]+glds[256]; C: h1s[16384]
  float* xh   = smem;
  float* glds = smem + 1024;
  float* h1s  = smem;
  u64*  tokred = (u64*)(smem + 1024);          // aliases glds; disjoint lifetime

  int tid = threadIdx.x, blk = blockIdx.x;
  int b = (blk & 7) | ((blk >> 6) << 3), jgrp = (blk >> 3) & 7, j0 = jgrp*64;
  int g = tid >> 6, jj = tid & 63;
  int rowA = g*512 + j0 + jj;
  int vl = tid >> 5, bb = tid & 31, wv = tid >> 6, lane = tid & 63;
  int v0 = blk * 64;

  float* HSf = (float*)(ws + OFF_HS);
  u64* PART = (u64*)(ws + OFF_PART);
  BarSlot* bars = (BarSlot*)ws;
  BarSlot* bar_b = bars + 128 + b;
  BarSlot* bar_f = bars + 192;
  float bA = b0v[rowA];
  float bB = b1v[rowA];
  int cls = *clsp;
  u32 tgt_b = 0, tgt_f = 0;
  const float4* wA1 = (const float4*)(W0i + (size_t)rowA*256);
  const float4* wA2 = (const float4*)(W0h + (size_t)rowA*512);
  const float4* wB1 = (const float4*)(W1i + (size_t)rowA*512);
  const float4* wB2 = (const float4*)(W1h + (size_t)rowA*512);

  for (int step = 0; step < 127; ++step){
    int p = step & 1;
    float* h0r = HSf + (p ? HS_H0B : HS_H0A);
    float* h0w = HSf + (p ? HS_H0A : HS_H0B);
    float* h1r = HSf + (p ? HS_H1B : HS_H1A);
    float* h1w = HSf + (p ? HS_H1A : HS_H1B);

    // ---- resolve token for this block's batch ----
    int t_b;
    if (step == 0){ t_b = cls; }
    else {
      u64 pk = 0;
      for (int r = tid; r < 1000; r += 256){ u64 q2 = PART[(size_t)b*1024 + r]; if (q2 > pk) pk = q2; }
      #pragma unroll
      for (int d = 32; d; d >>= 1){ u64 o = shfl_down_u64(pk, d); if (o > pk) pk = o; }
      if (lane == 0) tokred[wv] = pk;
      __syncthreads();
      if (tid == 0){
        u64 m = tokred[0];
        for (int w2 = 1; w2 < 4; ++w2) if (tokred[w2] > m) m = tokred[w2];
        u32 tk = 0xFFFFFFFFu - (u32)(m & 0xFFFFFFFFull);
        if (tk >= (u32)Vz) tk = 0;
        xh[1023] = __uint_as_float(tk);
      }
      __syncthreads();
      t_b = (int)__float_as_uint(xh[1023]);
    }

    // ---- phase A: dec0 cell ----
    xh[tid]       = oemb[(size_t)t_b*Ez + tid];
    xh[256 + tid] = h0r[b*512 + tid];
    xh[512 + tid] = h0r[b*512 + 256 + tid];
    __syncthreads();
    float acc = bA;
    #pragma unroll 16
    for (int k4 = 0; k4 < 64; ++k4){ float4 w = wA1[k4]; ACC4(w, xh + (k4<<2)); }
    #pragma unroll 16
    for (int k4 = 0; k4 < 128; ++k4){ float4 w = wA2[k4]; ACC4(w, xh + 256 + (k4<<2)); }
    glds[tid] = acc;
    __syncthreads();
    if (tid < 64){
      int j = j0 + tid;
      float iv = sigf(glds[tid]), fv = sigf(glds[64+tid]);
      float gv = tanhf(glds[128+tid]), ov = sigf(glds[192+tid]);
      float* c0 = HSf + HS_C0;
      float cold = c0[b*512 + j], cnew = fv*cold + iv*gv;
      c0[b*512 + j] = cnew;
      h0w[b*512 + j] = ov*tanhf(cnew);
    }
    block_bar(bar_b, 8, ++tgt_b);

    // ---- phase B: dec1 cell ----
    xh[tid]       = h0w[b*512 + tid];
    xh[256 + tid] = h0w[b*512 + 256 + tid];
    xh[512 + tid] = h1r[b*512 + tid];
    xh[768 + tid] = h1r[b*512 + 256 + tid];
    __syncthreads();
    acc = bB;
    #pragma unroll 16
    for (int k4 = 0; k4 < 128; ++k4){ float4 w = wB1[k4]; ACC4(w, xh + (k4<<2)); }
    #pragma unroll 16
    for (int k4 = 0; k4 < 128; ++k4){ float4 w = wB2[k4]; ACC4(w, xh + 512 + (k4<<2)); }
    glds[tid] = acc;
    __syncthreads();
    if (tid < 64){
      int j = j0 + tid;
      float iv = sigf(glds[tid]), fv = sigf(glds[64+tid]);
      float gv = tanhf(glds[128+tid]), ov = sigf(glds[192+tid]);
      float* c1 = HSf + HS_C1;
      float cold = c1[b*512 + j], cnew = fv*cold + iv*gv;
      c1[b*512 + j] = cnew;
      h1w[b*512 + j] = ov*tanhf(cnew);
    }
    block_bar(bar_f, 256, ++tgt_f);

    // ---- phase C: linear [32,512]x[16000,512]^T (f32), store, argmax partials ----
    // stage h1 with +4*b rotation: float4 loads aligned, <=4-way bank conflict
    for (int i2 = tid; i2 < 16384; i2 += 256){
      int b2 = i2 >> 9, k2 = i2 & 511;
      h1s[(i2 & ~511) | ((k2 + 4*b2) & 511)] = h1w[i2];
    }
    __syncthreads();
    if (blk < 250){
      int v8 = v0 + (vl<<3);
      float a[8];
      #pragma unroll
      for (int t = 0; t < 8; ++t) a[t] = linbv[v8 + t];
      const float4* wc = (const float4*)(linW + (size_t)v8*512);
      const float* hrow = h1s + (bb<<9);
      for (int k4 = 0; k4 < 128; ++k4){
        float4 hx = *(const float4*)(hrow + (((k4<<2) + 4*bb) & 511));
        #pragma unroll
        for (int t = 0; t < 8; ++t){
          float4 w = wc[t*128 + k4];
          a[t]=fmaf(w.x,hx.x,a[t]); a[t]=fmaf(w.y,hx.y,a[t]);
          a[t]=fmaf(w.z,hx.z,a[t]); a[t]=fmaf(w.w,hx.w,a[t]);
        }
      }
      float* orow = out + ((size_t)bb*Tz + (size_t)(step+1))*Vz + v8;
      *(float4*)(orow)     = make_float4(a[0],a[1],a[2],a[3]);
      *(float4*)(orow + 4) = make_float4(a[4],a[5],a[6],a[7]);
      if (step == 0){
        float* zrow = out + (size_t)bb*Tz*Vz + v8;   // frame 0 one-hot (scratch now dead)
        float f0[8];
        #pragma unroll
        for (int t = 0; t < 8; ++t) f0[t] = (v8 + t == cls) ? 1.f : 0.f;
        *(float4*)(zrow)     = make_float4(f0[0],f0[1],f0[2],f0[3]);
        *(float4*)(zrow + 4) = make_float4(f0[4],f0[5],f0[6],f0[7]);
      }
      u32 bk = f2ord(a[0]); u32 bvv = (u32)v8;
      #pragma unroll
      for (int t = 1; t < 8; ++t){ u32 k2 = f2ord(a[t]); if (k2 > bk){ bk = k2; bvv = (u32)(v8 + t); } }
      u64 pk = (((u64)bk)<<32) | (u64)(0xFFFFFFFFu - bvv);
      u64 o = shfl_down_u64(pk, 32); if (o > pk) pk = o;
      if (lane < 32) PART[(size_t)bb*1024 + blk*4 + wv] = pk;
    }
    if (step < 126) block_bar(bar_f, 256, ++tgt_f);
    else ++tgt_f;
  }
}

// ================= launch =================
extern "C" void kernel_launch(void* const* d_in, const int* in_sizes, int n_in,
                              void* d_out, int out_size, void* d_ws, size_t ws_size,
                              hipStream_t stream) {
  const int* inputs = (const int*)d_in[0];
  const int* cls    = (const int*)d_in[1];
  const float* in_emb = (const float*)d_in[2];
  const float* out_emb= (const float*)d_in[3];
  const float* e0f_Wih=(const float*)d_in[4],  *e0f_Whh=(const float*)d_in[5],  *e0f_b=(const float*)d_in[6];
  const float* e0b_Wih=(const float*)d_in[7],  *e0b_Whh=(const float*)d_in[8],  *e0b_b=(const float*)d_in[9];
  const float* e1f_Wih=(const float*)d_in[10], *e1f_Whh=(const float*)d_in[11], *e1f_b=(const float*)d_in[12];
  const float* e1b_Wih=(const float*)d_in[13], *e1b_Whh=(const float*)d_in[14], *e1b_b=(const float*)d_in[15];
  const float* d0_Wih =(const float*)d_in[16], *d0_Whh =(const float*)d_in[17], *d0_b =(const float*)d_in[18];
  const float* d1_Wih =(const float*)d_in[19], *d1_Whh =(const float*)d_in[20], *d1_b =(const float*)d_in[21];
  const float* linW   =(const float*)d_in[22], *linb   =(const float*)d_in[23];
  float* out = (float*)d_out;
  char* outc = (char*)d_out;
  char* ws = (char*)d_ws;

  hipMemsetAsync(ws, 0, 4096, stream);  // barrier slots
  k_init<<<1024, 256, 0, stream>>>(inputs, in_emb, outc, ws);
  k_enc<<<256, 256, 0, stream>>>(e0f_Wih, e0f_Whh, e0f_b, e0b_Wih, e0b_Whh, e0b_b, outc, ws, 0);
  k_enc<<<256, 256, 0, stream>>>(e1f_Wih, e1f_Whh, e1f_b, e1b_Wih, e1b_Whh, e1b_b, outc, ws, 1);
  k_dec<<<256, 256, 0, stream>>>(out_emb, d0_Wih, d0_Whh, d0_b, d1_Wih, d1_Whh, d1_b,
                                 linW, linb, cls, out, ws);
}